// Round 1
// baseline (40.395 us; speedup 1.0000x reference)
//
#include <hip/hip_runtime.h>
#include <hip/hip_bf16.h>

// Problem constants (from reference)
constexpr int B_  = 4;
constexpr int H_  = 128;
constexpr int W_  = 128;
constexpr int C_  = 64;    // input channels
constexpr int NH_ = 4;     // heads
constexpr int D_  = 16;    // per-head dim
constexpr int KK_ = 25;    // 5x5 patch

// Tiling
constexpr int TW_ = 8, TH_ = 8;          // pixel tile per block (64 px)
constexpr int HWID = TW_ + 4;            // halo width  = 12
constexpr int HHEI = TH_ + 4;            // halo height = 12
constexpr int ROWP = HWID + 1;           // padded halo row stride (pixels) = 13
constexpr int SLAB = HHEI * ROWP * D_ + 4;   // per-head r slab in floats = 2500 (stride !=0 mod 32 banks)
constexpr int PSTRIDE = KK_ + 2;         // 27 (odd stride -> conflict-free p exchange)
constexpr int PSLAB = TW_ * TH_ * PSTRIDE;   // 1728

__global__ __launch_bounds__(256) void rl8mh_kernel(
    const float* __restrict__ mainp, const float* __restrict__ refp,
    const float* __restrict__ wmain, const float* __restrict__ wref,
    float* __restrict__ out)
{
    // Union'd LDS: phase 1/2 -> r slabs (4*2500 f32 = 40000 B);
    // phase 3 -> per-head softmax exchange (4*1728 f32 = 27648 B)
    __shared__ float sm[NH_ * SLAB];

    const int tid  = threadIdx.x;
    const int lane = tid & 63;
    // wave id == head id; force to SGPR so weight indexing is scalar
    const int n = __builtin_amdgcn_readfirstlane(tid >> 6);

    const int x0 = blockIdx.x * TW_;
    const int y0 = blockIdx.y * TH_;
    const int b  = blockIdx.z;

    // ---------------- Phase 1: stage r for the 12x12 halo (this wave's head) ---------------
    {
        const float* wr = wref + n * C_ * D_;
        #pragma unroll
        for (int rnd = 0; rnd < 3; ++rnd) {
            int hp = rnd * 64 + lane;               // 0..191, valid < 144
            if (hp < HHEI * HWID) {
                int hy = hp / HWID;
                int hx = hp - hy * HWID;
                int gy = y0 + hy - 2;
                int gx = x0 + hx - 2;
                float acc[D_] = {};
                if (gy >= 0 && gy < H_ && gx >= 0 && gx < W_) {
                    const float4* row = reinterpret_cast<const float4*>(
                        refp + (((size_t)b * H_ + gy) * W_ + gx) * C_);
                    #pragma unroll 4
                    for (int c4 = 0; c4 < C_ / 4; ++c4) {
                        float4 rv = row[c4];
                        const float* wc = wr + c4 * 4 * D_;
                        #pragma unroll
                        for (int d = 0; d < D_; ++d) {
                            acc[d] = fmaf(rv.x, wc[d],
                                     fmaf(rv.y, wc[D_ + d],
                                     fmaf(rv.z, wc[2 * D_ + d],
                                     fmaf(rv.w, wc[3 * D_ + d], acc[d]))));
                        }
                    }
                }
                // write 16 f32 as 4x float4 with d-block XOR swizzle (bank spread)
                int base = n * SLAB + (hy * ROWP + hx) * D_;
                int sw   = hx & 3;
                #pragma unroll
                for (int blk = 0; blk < 4; ++blk) {
                    float4 v = make_float4(acc[blk * 4 + 0], acc[blk * 4 + 1],
                                           acc[blk * 4 + 2], acc[blk * 4 + 3]);
                    *reinterpret_cast<float4*>(&sm[base + ((blk ^ sw) << 2)]) = v;
                }
            }
        }
    }
    __syncthreads();

    // ---------------- Phase 2: q, logits, softmax (lane = pixel, wave = head) --------------
    const int px  = lane;            // 0..63
    const int py  = px >> 3;
    const int pxx = px & 7;
    const int gy  = y0 + py;
    const int gx  = x0 + pxx;

    float q[D_] = {};
    {
        const float* wm = wmain + n * C_ * D_;
        const float4* row = reinterpret_cast<const float4*>(
            mainp + (((size_t)b * H_ + gy) * W_ + gx) * C_);
        #pragma unroll 4
        for (int c4 = 0; c4 < C_ / 4; ++c4) {
            float4 mv = row[c4];
            const float* wc = wm + c4 * 4 * D_;
            #pragma unroll
            for (int d = 0; d < D_; ++d) {
                q[d] = fmaf(mv.x, wc[d],
                       fmaf(mv.y, wc[D_ + d],
                       fmaf(mv.z, wc[2 * D_ + d],
                       fmaf(mv.w, wc[3 * D_ + d], q[d]))));
            }
        }
    }

    float lg[KK_];
    #pragma unroll
    for (int ky = 0; ky < 5; ++ky) {
        #pragma unroll
        for (int kx = 0; kx < 5; ++kx) {
            int hy = py + ky;            // halo coords (offset -2 already folded in)
            int hx = pxx + kx;
            int base = n * SLAB + (hy * ROWP + hx) * D_;
            int sw   = hx & 3;
            float a = 0.f;
            #pragma unroll
            for (int blk = 0; blk < 4; ++blk) {
                float4 rv = *reinterpret_cast<const float4*>(&sm[base + ((blk ^ sw) << 2)]);
                a = fmaf(rv.x, q[blk * 4 + 0], a);
                a = fmaf(rv.y, q[blk * 4 + 1], a);
                a = fmaf(rv.z, q[blk * 4 + 2], a);
                a = fmaf(rv.w, q[blk * 4 + 3], a);
            }
            lg[ky * 5 + kx] = a;
        }
    }

    // in-thread softmax over 25
    float m = lg[0];
    #pragma unroll
    for (int k = 1; k < KK_; ++k) m = fmaxf(m, lg[k]);
    float s = 0.f;
    #pragma unroll
    for (int k = 0; k < KK_; ++k) { lg[k] = __expf(lg[k] - m); s += lg[k]; }
    float inv = 1.0f / s;

    // ---------------- Phase 3: head-average via LDS exchange --------------------------------
    __syncthreads();   // all r reads done; safe to overwrite sm
    #pragma unroll
    for (int k = 0; k < KK_; ++k) sm[n * PSLAB + px * PSTRIDE + k] = lg[k] * inv;
    __syncthreads();

    for (int i = tid; i < TW_ * TH_ * KK_; i += 256) {
        int p2 = i / KK_;
        int k  = i - p2 * KK_;
        int off = p2 * PSTRIDE + k;
        float v = 0.25f * (sm[off] + sm[PSLAB + off] + sm[2 * PSLAB + off] + sm[3 * PSLAB + off]);
        int py2 = p2 >> 3;
        int px2 = p2 & 7;
        out[(((size_t)b * H_ + (y0 + py2)) * W_ + (x0 + px2)) * KK_ + k] = v;
    }
}

extern "C" void kernel_launch(void* const* d_in, const int* in_sizes, int n_in,
                              void* d_out, int out_size, void* d_ws, size_t ws_size,
                              hipStream_t stream) {
    const float* mainp = (const float*)d_in[0];
    const float* refp  = (const float*)d_in[1];
    const float* wmain = (const float*)d_in[2];
    const float* wref  = (const float*)d_in[3];
    float* outp = (float*)d_out;

    dim3 grid(W_ / TW_, H_ / TH_, B_);
    rl8mh_kernel<<<grid, dim3(256), 0, stream>>>(mainp, refp, wmain, wref, outp);
}

// Round 2
// 39.939 us; speedup vs baseline: 1.0114x; 1.0114x over previous
//
#include <hip/hip_runtime.h>
#include <hip/hip_bf16.h>

// Problem constants (from reference)
constexpr int B_  = 4;
constexpr int H_  = 128;
constexpr int W_  = 128;
constexpr int C_  = 64;    // input channels
constexpr int NH_ = 4;     // heads
constexpr int D_  = 16;    // per-head dim
constexpr int KK_ = 25;    // 5x5 patch

// Attention tiling
constexpr int TW_ = 8, TH_ = 8;          // pixel tile per block (64 px)
constexpr int HWID = TW_ + 4;            // halo width  = 12
constexpr int HHEI = TH_ + 4;            // halo height = 12
constexpr int PXS  = 68;                 // padded pixel stride in LDS (f32 words); 68%32=4 -> bank spread
constexpr int HALO_F32 = HHEI * HWID * PXS;  // 9792 f32 = 39168 B
constexpr int PSTRIDE = KK_ + 2;         // 27 (odd -> conflict-free prob exchange)
constexpr int PSLAB = TW_ * TH_ * PSTRIDE;   // 1728 (4*1728=6912 <= 9792, fits in sm)

// ---------------------------------------------------------------------------
// Kernel A: r projection, computed exactly once per (pixel, head).
// ws layout: r[pixel][n*16+d], pixel = ((b*H+y)*W+x), f32.
// ---------------------------------------------------------------------------
__global__ __launch_bounds__(256) void proj_r_kernel(
    const float* __restrict__ refp, const float* __restrict__ wref,
    float* __restrict__ rws)
{
    const int tid  = threadIdx.x;
    const int lane = tid & 63;
    const int n = __builtin_amdgcn_readfirstlane(tid >> 6);  // wave = head

    const size_t p = (size_t)blockIdx.x * 64 + lane;         // pixel id

    // Batch all 16 float4 input loads -> hide HBM latency in-thread.
    const float4* row = reinterpret_cast<const float4*>(refp + p * C_);
    float4 rv[16];
    #pragma unroll
    for (int i = 0; i < 16; ++i) rv[i] = row[i];

    const float* wr = wref + n * C_ * D_;   // wave-uniform -> scalar loads
    float acc[D_] = {};
    #pragma unroll
    for (int c4 = 0; c4 < 16; ++c4) {
        const float* wc = wr + c4 * 4 * D_;
        #pragma unroll
        for (int d = 0; d < D_; ++d) {
            acc[d] = fmaf(rv[c4].x, wc[d],
                     fmaf(rv[c4].y, wc[D_ + d],
                     fmaf(rv[c4].z, wc[2 * D_ + d],
                     fmaf(rv[c4].w, wc[3 * D_ + d], acc[d]))));
        }
    }

    float4* dst = reinterpret_cast<float4*>(rws + p * 64 + n * 16);
    #pragma unroll
    for (int b2 = 0; b2 < 4; ++b2)
        dst[b2] = make_float4(acc[4 * b2], acc[4 * b2 + 1], acc[4 * b2 + 2], acc[4 * b2 + 3]);
}

// ---------------------------------------------------------------------------
// Kernel B: q projection (in-register) + local attention + softmax + head avg.
// r-halo comes precomputed from ws -> phase 1 is a pure coalesced copy.
// ---------------------------------------------------------------------------
__global__ __launch_bounds__(256, 4) void attn_kernel(
    const float* __restrict__ mainp, const float* __restrict__ wmain,
    const float* __restrict__ rws, float* __restrict__ out)
{
    __shared__ float sm[HALO_F32];

    const int tid  = threadIdx.x;
    const int lane = tid & 63;
    const int n = __builtin_amdgcn_readfirstlane(tid >> 6);  // wave = head

    const int x0 = blockIdx.x * TW_;
    const int y0 = blockIdx.y * TH_;
    const int b  = blockIdx.z;

    // ---- Phase 1: copy 12x12 halo of r (144 px * 64 f32 = 2304 float4) ----
    // 16 consecutive threads handle one pixel -> fully coalesced 256B/pixel.
    #pragma unroll
    for (int t = 0; t < 9; ++t) {
        int j  = t * 256 + tid;          // 0..2303
        int hp = j >> 4;                 // halo pixel 0..143
        int c4 = j & 15;                 // float4 index within pixel
        int hy = hp / HWID;
        int hx = hp - hy * HWID;
        int gy = y0 + hy - 2;
        int gx = x0 + hx - 2;
        float4 v = make_float4(0.f, 0.f, 0.f, 0.f);
        if ((unsigned)gy < (unsigned)H_ && (unsigned)gx < (unsigned)W_) {
            v = *reinterpret_cast<const float4*>(
                rws + (((size_t)b * H_ + gy) * W_ + gx) * 64 + c4 * 4);
        }
        *reinterpret_cast<float4*>(&sm[hp * PXS + c4 * 4]) = v;
    }
    __syncthreads();

    // ---- Phase 2: q in-register, logits from LDS, softmax ----
    const int py = lane >> 3;
    const int px = lane & 7;
    const int gy = y0 + py;
    const int gx = x0 + px;

    // Batched main-row loads.
    const float4* row = reinterpret_cast<const float4*>(
        mainp + (((size_t)b * H_ + gy) * W_ + gx) * C_);
    float4 mv[16];
    #pragma unroll
    for (int i = 0; i < 16; ++i) mv[i] = row[i];

    const float* wm = wmain + n * C_ * D_;
    float q[D_] = {};
    #pragma unroll
    for (int c4 = 0; c4 < 16; ++c4) {
        const float* wc = wm + c4 * 4 * D_;
        #pragma unroll
        for (int d = 0; d < D_; ++d) {
            q[d] = fmaf(mv[c4].x, wc[d],
                   fmaf(mv[c4].y, wc[D_ + d],
                   fmaf(mv[c4].z, wc[2 * D_ + d],
                   fmaf(mv[c4].w, wc[3 * D_ + d], q[d]))));
        }
    }

    float lg[KK_];
    #pragma unroll
    for (int ky = 0; ky < 5; ++ky) {
        #pragma unroll
        for (int kx = 0; kx < 5; ++kx) {
            int base = ((py + ky) * HWID + (px + kx)) * PXS + n * 16;
            float a = 0.f;
            #pragma unroll
            for (int blk = 0; blk < 4; ++blk) {
                float4 rv = *reinterpret_cast<const float4*>(&sm[base + 4 * blk]);
                a = fmaf(rv.x, q[blk * 4 + 0], a);
                a = fmaf(rv.y, q[blk * 4 + 1], a);
                a = fmaf(rv.z, q[blk * 4 + 2], a);
                a = fmaf(rv.w, q[blk * 4 + 3], a);
            }
            lg[ky * 5 + kx] = a;
        }
    }

    // in-thread softmax over 25
    float m = lg[0];
    #pragma unroll
    for (int k = 1; k < KK_; ++k) m = fmaxf(m, lg[k]);
    float s = 0.f;
    #pragma unroll
    for (int k = 0; k < KK_; ++k) { lg[k] = __expf(lg[k] - m); s += lg[k]; }
    const float inv = 1.0f / s;

    // ---- Phase 3: head-average via LDS exchange ----
    __syncthreads();   // all r reads done; safe to overwrite sm
    #pragma unroll
    for (int k = 0; k < KK_; ++k) sm[n * PSLAB + lane * PSTRIDE + k] = lg[k] * inv;
    __syncthreads();

    for (int i = tid; i < TW_ * TH_ * KK_; i += 256) {
        int p2 = i / KK_;
        int k  = i - p2 * KK_;
        int off = p2 * PSTRIDE + k;
        float v = 0.25f * (sm[off] + sm[PSLAB + off] + sm[2 * PSLAB + off] + sm[3 * PSLAB + off]);
        int py2 = p2 >> 3;
        int px2 = p2 & 7;
        out[(((size_t)b * H_ + (y0 + py2)) * W_ + (x0 + px2)) * KK_ + k] = v;
    }
}

// ---------------------------------------------------------------------------
// Fallback: round-1 fused kernel (used only if ws is too small).
// ---------------------------------------------------------------------------
constexpr int ROWP = HWID + 1;
constexpr int SLAB = HHEI * ROWP * D_ + 4;

__global__ __launch_bounds__(256) void rl8mh_fused(
    const float* __restrict__ mainp, const float* __restrict__ refp,
    const float* __restrict__ wmain, const float* __restrict__ wref,
    float* __restrict__ out)
{
    __shared__ float sm[NH_ * SLAB];
    const int tid  = threadIdx.x;
    const int lane = tid & 63;
    const int n = __builtin_amdgcn_readfirstlane(tid >> 6);
    const int x0 = blockIdx.x * TW_;
    const int y0 = blockIdx.y * TH_;
    const int b  = blockIdx.z;
    {
        const float* wr = wref + n * C_ * D_;
        #pragma unroll
        for (int rnd = 0; rnd < 3; ++rnd) {
            int hp = rnd * 64 + lane;
            if (hp < HHEI * HWID) {
                int hy = hp / HWID;
                int hx = hp - hy * HWID;
                int gy = y0 + hy - 2;
                int gx = x0 + hx - 2;
                float acc[D_] = {};
                if (gy >= 0 && gy < H_ && gx >= 0 && gx < W_) {
                    const float4* row = reinterpret_cast<const float4*>(
                        refp + (((size_t)b * H_ + gy) * W_ + gx) * C_);
                    #pragma unroll 4
                    for (int c4 = 0; c4 < C_ / 4; ++c4) {
                        float4 rv = row[c4];
                        const float* wc = wr + c4 * 4 * D_;
                        #pragma unroll
                        for (int d = 0; d < D_; ++d) {
                            acc[d] = fmaf(rv.x, wc[d],
                                     fmaf(rv.y, wc[D_ + d],
                                     fmaf(rv.z, wc[2 * D_ + d],
                                     fmaf(rv.w, wc[3 * D_ + d], acc[d]))));
                        }
                    }
                }
                int base = n * SLAB + (hy * ROWP + hx) * D_;
                int sw   = hx & 3;
                #pragma unroll
                for (int blk = 0; blk < 4; ++blk) {
                    float4 v = make_float4(acc[blk * 4 + 0], acc[blk * 4 + 1],
                                           acc[blk * 4 + 2], acc[blk * 4 + 3]);
                    *reinterpret_cast<float4*>(&sm[base + ((blk ^ sw) << 2)]) = v;
                }
            }
        }
    }
    __syncthreads();
    const int px  = lane;
    const int py  = px >> 3;
    const int pxx = px & 7;
    const int gy  = y0 + py;
    const int gx  = x0 + pxx;
    float q[D_] = {};
    {
        const float* wm = wmain + n * C_ * D_;
        const float4* row = reinterpret_cast<const float4*>(
            mainp + (((size_t)b * H_ + gy) * W_ + gx) * C_);
        #pragma unroll 4
        for (int c4 = 0; c4 < C_ / 4; ++c4) {
            float4 mv = row[c4];
            const float* wc = wm + c4 * 4 * D_;
            #pragma unroll
            for (int d = 0; d < D_; ++d) {
                q[d] = fmaf(mv.x, wc[d],
                       fmaf(mv.y, wc[D_ + d],
                       fmaf(mv.z, wc[2 * D_ + d],
                       fmaf(mv.w, wc[3 * D_ + d], q[d]))));
            }
        }
    }
    float lg[KK_];
    #pragma unroll
    for (int ky = 0; ky < 5; ++ky) {
        #pragma unroll
        for (int kx = 0; kx < 5; ++kx) {
            int hy = py + ky;
            int hx = pxx + kx;
            int base = n * SLAB + (hy * ROWP + hx) * D_;
            int sw   = hx & 3;
            float a = 0.f;
            #pragma unroll
            for (int blk = 0; blk < 4; ++blk) {
                float4 rv = *reinterpret_cast<const float4*>(&sm[base + ((blk ^ sw) << 2)]);
                a = fmaf(rv.x, q[blk * 4 + 0], a);
                a = fmaf(rv.y, q[blk * 4 + 1], a);
                a = fmaf(rv.z, q[blk * 4 + 2], a);
                a = fmaf(rv.w, q[blk * 4 + 3], a);
            }
            lg[ky * 5 + kx] = a;
        }
    }
    float m = lg[0];
    #pragma unroll
    for (int k = 1; k < KK_; ++k) m = fmaxf(m, lg[k]);
    float s = 0.f;
    #pragma unroll
    for (int k = 0; k < KK_; ++k) { lg[k] = __expf(lg[k] - m); s += lg[k]; }
    float inv = 1.0f / s;
    __syncthreads();
    #pragma unroll
    for (int k = 0; k < KK_; ++k) sm[n * PSLAB + lane * PSTRIDE + k] = lg[k] * inv;
    __syncthreads();
    for (int i = tid; i < TW_ * TH_ * KK_; i += 256) {
        int p2 = i / KK_;
        int k  = i - p2 * KK_;
        int off = p2 * PSTRIDE + k;
        float v = 0.25f * (sm[off] + sm[PSLAB + off] + sm[2 * PSLAB + off] + sm[3 * PSLAB + off]);
        int py2 = p2 >> 3;
        int px2 = p2 & 7;
        out[(((size_t)b * H_ + (y0 + py2)) * W_ + (x0 + px2)) * KK_ + k] = v;
    }
}

extern "C" void kernel_launch(void* const* d_in, const int* in_sizes, int n_in,
                              void* d_out, int out_size, void* d_ws, size_t ws_size,
                              hipStream_t stream) {
    const float* mainp = (const float*)d_in[0];
    const float* refp  = (const float*)d_in[1];
    const float* wmain = (const float*)d_in[2];
    const float* wref  = (const float*)d_in[3];
    float* outp = (float*)d_out;

    const size_t need = (size_t)B_ * H_ * W_ * NH_ * D_ * sizeof(float);  // 16.78 MB
    dim3 gridB(W_ / TW_, H_ / TH_, B_);

    if (ws_size >= need) {
        float* rws = (float*)d_ws;
        proj_r_kernel<<<dim3((B_ * H_ * W_) / 64), dim3(256), 0, stream>>>(refp, wref, rws);
        attn_kernel<<<gridB, dim3(256), 0, stream>>>(mainp, wmain, rws, outp);
    } else {
        rl8mh_fused<<<gridB, dim3(256), 0, stream>>>(mainp, refp, wmain, wref, outp);
    }
}

// Round 3
// 33.847 us; speedup vs baseline: 1.1934x; 1.1800x over previous
//
#include <hip/hip_runtime.h>
#include <hip/hip_bf16.h>

typedef _Float16 f16;
typedef f16 f16x2 __attribute__((ext_vector_type(2)));
typedef f16 f16x8 __attribute__((ext_vector_type(8)));
typedef float f32x4 __attribute__((ext_vector_type(4)));

constexpr int B_  = 4;
constexpr int H_  = 128;
constexpr int W_  = 128;
constexpr int C_  = 64;
constexpr int NH_ = 4;
constexpr int D_  = 16;
constexpr int KK_ = 25;

constexpr int TW_  = 8, TH_ = 8;
constexpr int HWID = 12, HHEI = 12;
constexpr int NPX  = HHEI * HWID;        // 144 halo pixels
constexpr int RSTR = 72;                 // f16 per LDS pixel row (144 B; 36 dw -> 4-bank shift/px)
constexpr int RBYTES = NPX * RSTR * 2;   // 20736
constexpr int QBYTES = 64 * RSTR * 2;    // 9216
constexpr int PSTRIDE = KK_ + 2;         // 27
constexpr int PSLAB  = 64 * PSTRIDE;     // 1728 (4*1728*4B = 27648 <= 29952)

#if __has_builtin(__builtin_amdgcn_fdot2)
#define FDOT2(a, b, c) __builtin_amdgcn_fdot2((a), (b), (c), false)
#else
#define FDOT2(a, b, c) fmaf((float)(a)[1], (float)(b)[1], fmaf((float)(a)[0], (float)(b)[0], (c)))
#endif

__device__ __forceinline__ int div12(int x) { return (x * 171) >> 11; }  // exact for 0..143

__global__ __launch_bounds__(256, 4) void rl8mh_mfma(
    const float* __restrict__ mainp, const float* __restrict__ refp,
    const float* __restrict__ wmain, const float* __restrict__ wref,
    float* __restrict__ out)
{
    __shared__ __align__(16) unsigned char smraw[RBYTES + QBYTES];  // 29952 B
    f16*   rbuf = (f16*)smraw;              // [144 px][72 f16], head chunks XOR-swizzled
    f16*   qbuf = (f16*)(smraw + RBYTES);   // [64 px][72 f16]
    float* xbuf = (float*)smraw;            // prob exchange (after barrier)

    const int tid = threadIdx.x;
    const int l   = tid & 63;
    const int n   = __builtin_amdgcn_readfirstlane(tid >> 6);  // wave = head
    const int row = l & 15;    // MFMA row / col index
    const int kg  = l >> 4;    // k-group (0..3)

    const int x0 = blockIdx.x * TW_;
    const int y0 = blockIdx.y * TH_;
    const int b  = blockIdx.z;

    // ---- B fragments (weights) for head n: B[k][col], k = s*32 + kg*8 + i, col = row ----
    f16x8 bm[2], br[2];
    {
        const float* wm = wmain + n * C_ * D_;
        const float* wr = wref  + n * C_ * D_;
        #pragma unroll
        for (int s = 0; s < 2; ++s) {
            union { f16x8 v; f16 e[8]; } um, ur;
            #pragma unroll
            for (int i = 0; i < 8; ++i) {
                int k = s * 32 + kg * 8 + i;
                um.e[i] = (f16)wm[k * D_ + row];
                ur.e[i] = (f16)wr[k * D_ + row];
            }
            bm[s] = um.v; br[s] = ur.v;
        }
    }

    // ---- halo r projection via MFMA: 9 tiles x 16 halo px, K=64 in 2 steps ----
    #pragma unroll
    for (int t = 0; t < 9; ++t) {
        int hp = t * 16 + row;
        int hy = div12(hp);
        int hx = hp - hy * 12;
        int gy = y0 + hy - 2, gx = x0 + hx - 2;
        bool ok = ((unsigned)gy < (unsigned)H_) && ((unsigned)gx < (unsigned)W_);
        float4 a00 = make_float4(0.f, 0.f, 0.f, 0.f), a01 = a00, a10 = a00, a11 = a00;
        if (ok) {
            const float* src = refp + (((size_t)b * H_ + gy) * W_ + gx) * C_ + kg * 8;
            a00 = *(const float4*)(src);
            a01 = *(const float4*)(src + 4);
            a10 = *(const float4*)(src + 32);
            a11 = *(const float4*)(src + 36);
        }
        union { f16x8 v; f16 e[8]; } A0, A1;
        A0.e[0]=(f16)a00.x; A0.e[1]=(f16)a00.y; A0.e[2]=(f16)a00.z; A0.e[3]=(f16)a00.w;
        A0.e[4]=(f16)a01.x; A0.e[5]=(f16)a01.y; A0.e[6]=(f16)a01.z; A0.e[7]=(f16)a01.w;
        A1.e[0]=(f16)a10.x; A1.e[1]=(f16)a10.y; A1.e[2]=(f16)a10.z; A1.e[3]=(f16)a10.w;
        A1.e[4]=(f16)a11.x; A1.e[5]=(f16)a11.y; A1.e[6]=(f16)a11.z; A1.e[7]=(f16)a11.w;
        f32x4 acc = {0.f, 0.f, 0.f, 0.f};
        acc = __builtin_amdgcn_mfma_f32_16x16x32_f16(A0.v, br[0], acc, 0, 0, 0);
        acc = __builtin_amdgcn_mfma_f32_16x16x32_f16(A1.v, br[1], acc, 0, 0, 0);
        // C: col = l&15 (=row var), px = t*16 + kg*4 + r2
        #pragma unroll
        for (int r2 = 0; r2 < 4; ++r2) {
            int cpx = t * 16 + kg * 4 + r2;
            int chy = div12(cpx);
            rbuf[cpx * RSTR + ((n * 16 + row) ^ ((chy & 7) * 8))] = (f16)acc[r2];
        }
    }

    // ---- q projection via MFMA: 4 tiles of own 64 px ----
    #pragma unroll
    for (int t = 0; t < 4; ++t) {
        int px = t * 16 + row;
        int gy = y0 + (px >> 3), gx = x0 + (px & 7);
        const float* src = mainp + (((size_t)b * H_ + gy) * W_ + gx) * C_ + kg * 8;
        float4 a00 = *(const float4*)(src);
        float4 a01 = *(const float4*)(src + 4);
        float4 a10 = *(const float4*)(src + 32);
        float4 a11 = *(const float4*)(src + 36);
        union { f16x8 v; f16 e[8]; } A0, A1;
        A0.e[0]=(f16)a00.x; A0.e[1]=(f16)a00.y; A0.e[2]=(f16)a00.z; A0.e[3]=(f16)a00.w;
        A0.e[4]=(f16)a01.x; A0.e[5]=(f16)a01.y; A0.e[6]=(f16)a01.z; A0.e[7]=(f16)a01.w;
        A1.e[0]=(f16)a10.x; A1.e[1]=(f16)a10.y; A1.e[2]=(f16)a10.z; A1.e[3]=(f16)a10.w;
        A1.e[4]=(f16)a11.x; A1.e[5]=(f16)a11.y; A1.e[6]=(f16)a11.z; A1.e[7]=(f16)a11.w;
        f32x4 acc = {0.f, 0.f, 0.f, 0.f};
        acc = __builtin_amdgcn_mfma_f32_16x16x32_f16(A0.v, bm[0], acc, 0, 0, 0);
        acc = __builtin_amdgcn_mfma_f32_16x16x32_f16(A1.v, bm[1], acc, 0, 0, 0);
        #pragma unroll
        for (int r2 = 0; r2 < 4; ++r2) {
            int cpx = t * 16 + kg * 4 + r2;
            qbuf[cpx * RSTR + ((n * 16 + row) ^ (((cpx >> 3) & 7) * 8))] = (f16)acc[r2];
        }
    }

    // ---- per-thread q fragment (wave-local LDS RAW; no barrier needed) ----
    const int py  = l >> 3;
    const int pxx = l & 7;
    const int qkey = (py & 7) * 8;
    f16x8 q0 = *(const f16x8*)&qbuf[l * RSTR + ((n * 16 + 0) ^ qkey)];
    f16x8 q1 = *(const f16x8*)&qbuf[l * RSTR + ((n * 16 + 8) ^ qkey)];
    const f16x2* q2a = (const f16x2*)&q0;
    const f16x2* q2b = (const f16x2*)&q1;

    // ---- logits: 25 offsets, 2x ds_read_b128 + 8 fdot2 each ----
    float lg[KK_];
    #pragma unroll
    for (int ky = 0; ky < 5; ++ky) {
        int hy  = py + ky;
        int key = (hy & 7) * 8;
        int rb  = hy * 12 + pxx;
        #pragma unroll
        for (int kx = 0; kx < 5; ++kx) {
            const f16* rp = &rbuf[(rb + kx) * RSTR];
            f16x8 r0 = *(const f16x8*)&rp[(n * 16 + 0) ^ key];
            f16x8 r1 = *(const f16x8*)&rp[(n * 16 + 8) ^ key];
            const f16x2* r2a = (const f16x2*)&r0;
            const f16x2* r2b = (const f16x2*)&r1;
            float a = 0.f;
            #pragma unroll
            for (int j = 0; j < 4; ++j) a = FDOT2(q2a[j], r2a[j], a);
            #pragma unroll
            for (int j = 0; j < 4; ++j) a = FDOT2(q2b[j], r2b[j], a);
            lg[ky * 5 + kx] = a;
        }
    }

    // ---- in-thread softmax over 25 ----
    float m = lg[0];
    #pragma unroll
    for (int k = 1; k < KK_; ++k) m = fmaxf(m, lg[k]);
    float s = 0.f;
    #pragma unroll
    for (int k = 0; k < KK_; ++k) { lg[k] = __expf(lg[k] - m); s += lg[k]; }
    const float inv = 1.0f / s;

    // ---- head-average via LDS exchange (f32) ----
    __syncthreads();   // all waves done reading rbuf/qbuf
    #pragma unroll
    for (int k = 0; k < KK_; ++k) xbuf[n * PSLAB + l * PSTRIDE + k] = lg[k] * inv;
    __syncthreads();

    for (int i = tid; i < TW_ * TH_ * KK_; i += 256) {
        int p2 = i / KK_;
        int k  = i - p2 * KK_;
        int off = p2 * PSTRIDE + k;
        float v = 0.25f * (xbuf[off] + xbuf[PSLAB + off] + xbuf[2 * PSLAB + off] + xbuf[3 * PSLAB + off]);
        out[(((size_t)b * H_ + (y0 + (p2 >> 3))) * W_ + (x0 + (p2 & 7))) * KK_ + k] = v;
    }
}

extern "C" void kernel_launch(void* const* d_in, const int* in_sizes, int n_in,
                              void* d_out, int out_size, void* d_ws, size_t ws_size,
                              hipStream_t stream) {
    const float* mainp = (const float*)d_in[0];
    const float* refp  = (const float*)d_in[1];
    const float* wmain = (const float*)d_in[2];
    const float* wref  = (const float*)d_in[3];
    float* outp = (float*)d_out;

    dim3 grid(W_ / TW_, H_ / TH_, B_);
    rl8mh_mfma<<<grid, dim3(256), 0, stream>>>(mainp, refp, wmain, wref, outp);
}